// Round 5
// baseline (1582.699 us; speedup 1.0000x reference)
//
#include <hip/hip_runtime.h>
#include <math.h>

#define BB 16
#define CC 256
#define HH 56
#define WW2 56
#define HWW 3136           // 56*56
#define NTOK 50176         // BB*HWW
#define NHD 8
#define HD 32
#define WSZ 7
#define WIN 49
#define NWIN 1024          // BB * 8 * 8
#define HID 1024
#define C3 768

typedef __attribute__((ext_vector_type(8))) short bf16x8;
typedef __attribute__((ext_vector_type(4))) float f32x4;

__device__ __forceinline__ float gelu_f(float x) {
    return 0.5f * x * (1.0f + erff(x * 0.70710678118654752f));
}

// ---------------- K1: NCHW -> token-major (b, p, c) ----------------
__global__ __launch_bounds__(256) void k_nchw_to_tok(const float* __restrict__ x,
                                                     float* __restrict__ xl) {
    __shared__ float tile[32][33];
    int b = blockIdx.z;
    int p0 = blockIdx.x * 32, c0 = blockIdx.y * 32;
    int tx = threadIdx.x, ty = threadIdx.y; // (32, 8)
    const float* xb = x + (size_t)b * CC * HWW;
    #pragma unroll
    for (int r = 0; r < 32; r += 8)
        tile[ty + r][tx] = xb[(size_t)(c0 + ty + r) * HWW + p0 + tx];
    __syncthreads();
    float* xlb = xl + (size_t)b * HWW * CC;
    #pragma unroll
    for (int r = 0; r < 32; r += 8)
        xlb[(size_t)(p0 + ty + r) * CC + c0 + tx] = tile[tx][ty + r];
}

// ---------------- token-major (b,p,c) -> NCHW (b,c,p) ----------------
__global__ __launch_bounds__(256) void k_tok_to_nchw(const float* __restrict__ zl,
                                                     float* __restrict__ out) {
    __shared__ float tile[32][33];
    int b = blockIdx.z;
    int p0 = blockIdx.x * 32, c0 = blockIdx.y * 32;
    int tx = threadIdx.x, ty = threadIdx.y;
    const float* zb = zl + (size_t)b * HWW * CC;
    #pragma unroll
    for (int r = 0; r < 32; r += 8)
        tile[ty + r][tx] = zb[(size_t)(p0 + ty + r) * CC + c0 + tx];
    __syncthreads();
    float* ob = out + (size_t)b * CC * HWW;
    #pragma unroll
    for (int r = 0; r < 32; r += 8)
        ob[(size_t)(c0 + ty + r) * HWW + p0 + tx] = tile[tx][ty + r];
}

// ---------------- K2: LayerNorm over C=256 per token ----------------
__global__ __launch_bounds__(256) void k_ln(const float* __restrict__ in,
                                            const float* __restrict__ w,
                                            const float* __restrict__ bia,
                                            float* __restrict__ out) {
    size_t t = blockIdx.x;
    int c = threadIdx.x;
    float v = in[t * CC + c];
    float s = v, sq = v * v;
    #pragma unroll
    for (int off = 32; off; off >>= 1) {
        s += __shfl_xor(s, off);
        sq += __shfl_xor(sq, off);
    }
    __shared__ float red[8];
    int wid = c >> 6, lane = c & 63;
    if (lane == 0) { red[wid] = s; red[4 + wid] = sq; }
    __syncthreads();
    s = red[0] + red[1] + red[2] + red[3];
    sq = red[4] + red[5] + red[6] + red[7];
    float m = s * (1.0f / CC);
    float var = sq * (1.0f / CC) - m * m;
    float rs = rsqrtf(var + 1e-6f);
    out[t * CC + c] = (v - m) * rs * w[c] + bia[c];
}

// ---------------- K3: window pos-enc (two depthwise 3x3 over 7x7 + gelu) ----------------
__global__ __launch_bounds__(256) void k_posenc(const float* __restrict__ xln,
                                                const float* __restrict__ w1,
                                                const float* __restrict__ w2,
                                                float* __restrict__ tout) {
    int win = blockIdx.x;
    int c = threadIdx.x;
    int b = win >> 6, wh = (win >> 3) & 7, ww = win & 7;
    const float* base = xln + ((size_t)b * HWW) * CC + c;
    float v[49];
    #pragma unroll
    for (int r = 0; r < 7; r++)
        #pragma unroll
        for (int s = 0; s < 7; s++)
            v[r * 7 + s] = base[(size_t)((wh * 7 + r) * WW2 + ww * 7 + s) * CC];
    float k1w[9], k2w[9];
    #pragma unroll
    for (int k = 0; k < 9; k++) { k1w[k] = w1[c * 9 + k]; k2w[k] = w2[c * 9 + k]; }
    float g[49];
    #pragma unroll
    for (int r = 0; r < 7; r++)
        #pragma unroll
        for (int s = 0; s < 7; s++) {
            float acc = 0.f;
            #pragma unroll
            for (int kr = 0; kr < 3; kr++)
                #pragma unroll
                for (int ks = 0; ks < 3; ks++) {
                    int rr = r + kr - 1, ss = s + ks - 1;
                    if (rr >= 0 && rr < 7 && ss >= 0 && ss < 7)
                        acc += v[rr * 7 + ss] * k1w[kr * 3 + ks];
                }
            g[r * 7 + s] = gelu_f(acc);
        }
    float* outp = tout + (size_t)win * WIN * CC + c;
    #pragma unroll
    for (int r = 0; r < 7; r++)
        #pragma unroll
        for (int s = 0; s < 7; s++) {
            float acc = 0.f;
            #pragma unroll
            for (int kr = 0; kr < 3; kr++)
                #pragma unroll
                for (int ks = 0; ks < 3; ks++) {
                    int rr = r + kr - 1, ss = s + ks - 1;
                    if (rr >= 0 && rr < 7 && ss >= 0 && ss < 7)
                        acc += g[rr * 7 + ss] * k2w[kr * 3 + ks];
                }
            outp[(size_t)(r * 7 + s) * CC] = v[r * 7 + s] + acc;
        }
}

// ---------------- split fp32 -> bf16 hi/lo (truncation; hi+lo exact to 2^-16 rel) ----
__device__ __forceinline__ void cvt_split4(float4 v, unsigned& h0, unsigned& h1,
                                           unsigned& l0, unsigned& l1) {
    unsigned ux = __float_as_uint(v.x), uy = __float_as_uint(v.y);
    unsigned uz = __float_as_uint(v.z), uw = __float_as_uint(v.w);
    unsigned hx = ux & 0xFFFF0000u, hy = uy & 0xFFFF0000u;
    unsigned hz = uz & 0xFFFF0000u, hw = uw & 0xFFFF0000u;
    float lx = v.x - __uint_as_float(hx);
    float ly = v.y - __uint_as_float(hy);
    float lz = v.z - __uint_as_float(hz);
    float lw = v.w - __uint_as_float(hw);
    h0 = (hx >> 16) | hy;
    h1 = (hz >> 16) | hw;
    l0 = (__float_as_uint(lx) >> 16) | (__float_as_uint(ly) & 0xFFFF0000u);
    l1 = (__float_as_uint(lz) >> 16) | (__float_as_uint(lw) & 0xFFFF0000u);
}

// ---------------- MFMA GEMM: Out[M,N] = A[M,K] @ Bw[N,K]^T + bias ----------------
// 128x128 tile, BK=32, 4 waves each computing 64x64 via 16x16x32 bf16 MFMA,
// split-precision 3-pass (Ah*Bh + Al*Bh + Ah*Bl) => fp32-accurate.
// EPI 0: plain store.  EPI 1: window-token -> (b,p) remap + residual add (N==256)
#define LDK 40   // padded bf16 row stride (80B: rows walk all 32 banks, 2-way free)
template <int EPI>
__global__ __launch_bounds__(256) void k_gemm_mfma(const float* __restrict__ A,
                                                   const float* __restrict__ Bw,
                                                   const float* __restrict__ bias,
                                                   float* __restrict__ Out,
                                                   float* __restrict__ resid,
                                                   int N, int K) {
    __shared__ __align__(16) unsigned short Ah[128 * LDK];
    __shared__ __align__(16) unsigned short Al[128 * LDK];
    __shared__ __align__(16) unsigned short Bh[128 * LDK];
    __shared__ __align__(16) unsigned short Bl[128 * LDK];
    const int tid = threadIdx.x;
    const int bm = blockIdx.y * 128;
    const int bn = blockIdx.x * 128;
    const int srow = tid >> 3;        // 0..31
    const int skf = (tid & 7) * 4;    // k-offset in floats: 0..28
    const int lane = tid & 63;
    const int wave = tid >> 6;
    const int wm = (wave & 1) * 64;
    const int wn = (wave >> 1) * 64;
    const int frow = lane & 15;
    const int fk = (lane >> 4) * 8;   // k-offset of this lane's fragment

    f32x4 acc[4][4] = {};

    for (int k0 = 0; k0 < K; k0 += 32) {
        if (k0) __syncthreads();
        #pragma unroll
        for (int h = 0; h < 4; ++h) {
            int row = srow + h * 32;
            float4 av = *reinterpret_cast<const float4*>(&A[(size_t)(bm + row) * K + k0 + skf]);
            float4 bv = *reinterpret_cast<const float4*>(&Bw[(size_t)(bn + row) * K + k0 + skf]);
            unsigned h0, h1, l0, l1;
            cvt_split4(av, h0, h1, l0, l1);
            *reinterpret_cast<uint2*>(&Ah[row * LDK + skf]) = make_uint2(h0, h1);
            *reinterpret_cast<uint2*>(&Al[row * LDK + skf]) = make_uint2(l0, l1);
            cvt_split4(bv, h0, h1, l0, l1);
            *reinterpret_cast<uint2*>(&Bh[row * LDK + skf]) = make_uint2(h0, h1);
            *reinterpret_cast<uint2*>(&Bl[row * LDK + skf]) = make_uint2(l0, l1);
        }
        __syncthreads();
        bf16x8 a_h[4], a_l[4], b_h[4], b_l[4];
        #pragma unroll
        for (int mi = 0; mi < 4; mi++) {
            int idx = (wm + mi * 16 + frow) * LDK + fk;
            a_h[mi] = *reinterpret_cast<const bf16x8*>(&Ah[idx]);
            a_l[mi] = *reinterpret_cast<const bf16x8*>(&Al[idx]);
        }
        #pragma unroll
        for (int nj = 0; nj < 4; nj++) {
            int idx = (wn + nj * 16 + frow) * LDK + fk;
            b_h[nj] = *reinterpret_cast<const bf16x8*>(&Bh[idx]);
            b_l[nj] = *reinterpret_cast<const bf16x8*>(&Bl[idx]);
        }
        #pragma unroll
        for (int mi = 0; mi < 4; mi++)
            #pragma unroll
            for (int nj = 0; nj < 4; nj++) {
                acc[mi][nj] = __builtin_amdgcn_mfma_f32_16x16x32_bf16(a_h[mi], b_h[nj], acc[mi][nj], 0, 0, 0);
                acc[mi][nj] = __builtin_amdgcn_mfma_f32_16x16x32_bf16(a_l[mi], b_h[nj], acc[mi][nj], 0, 0, 0);
                acc[mi][nj] = __builtin_amdgcn_mfma_f32_16x16x32_bf16(a_h[mi], b_l[nj], acc[mi][nj], 0, 0, 0);
            }
    }

    // epilogue: D layout col=lane&15, row=(lane>>4)*4+r
    const int rbase = (lane >> 4) * 4;
    #pragma unroll
    for (int mi = 0; mi < 4; mi++) {
        #pragma unroll
        for (int nj = 0; nj < 4; nj++) {
            int gcol = bn + wn + nj * 16 + frow;
            float bval = bias[gcol];
            #pragma unroll
            for (int r = 0; r < 4; r++) {
                int grow = bm + wm + mi * 16 + rbase + r;
                float val = acc[mi][nj][r] + bval;
                if (EPI == 0) {
                    Out[(size_t)grow * N + gcol] = val;
                } else {
                    int win = grow / 49, ii = grow - win * 49;
                    int b = win >> 6, wh = (win >> 3) & 7, ww = win & 7;
                    int rr = ii / 7, ss = ii - rr * 7;
                    size_t tok = (size_t)b * HWW + (size_t)((wh * 7 + rr) * WW2 + ww * 7 + ss);
                    resid[tok * CC + gcol] += val;
                }
            }
        }
    }
}

// ---------------- K5: windowed attention, one (win, head) per block ----------------
__global__ __launch_bounds__(256) void k_attn(const float* __restrict__ qkv,
                                              const float* __restrict__ rpb,
                                              float* __restrict__ O) {
    __shared__ float qs[49][32], ks[49][32], vs[49][32];
    __shared__ float S[49][52];
    const int tid = threadIdx.x;
    const int win = blockIdx.x >> 3;
    const int head = blockIdx.x & 7;
    const float* base = qkv + (size_t)win * WIN * C3 + head * HD;
    for (int idx = tid; idx < WIN * HD; idx += 256) {
        int i = idx >> 5, d = idx & 31;
        const float* bp = base + (size_t)i * C3 + d;
        qs[i][d] = bp[0] * 0.17677669529663687f; // 1/sqrt(32)
        ks[i][d] = bp[CC];
        vs[i][d] = bp[2 * CC];
    }
    __syncthreads();
    for (int idx = tid; idx < WIN * WIN; idx += 256) {
        int i = idx / 49, j = idx - i * 49;
        const float4* qp = reinterpret_cast<const float4*>(qs[i]);
        const float4* kp = reinterpret_cast<const float4*>(ks[j]);
        float acc = 0.f;
        #pragma unroll
        for (int d = 0; d < 8; d++) {
            float4 a = qp[d], b2 = kp[d];
            acc += a.x * b2.x + a.y * b2.y + a.z * b2.z + a.w * b2.w;
        }
        int ci = (i / 7) * 13 + (i % 7);
        int jr = 48 - j;
        int cj = (jr / 7) * 13 + (jr % 7);
        S[i][j] = acc + rpb[(ci + cj) * NHD + head];
    }
    __syncthreads();
    int wid = tid >> 6, lane = tid & 63;
    for (int row = wid; row < 49; row += 4) {
        float v = (lane < 49) ? S[row][lane] : -1e30f;
        float mx = v;
        #pragma unroll
        for (int off = 32; off; off >>= 1) mx = fmaxf(mx, __shfl_xor(mx, off));
        float e = (lane < 49) ? __expf(v - mx) : 0.f;
        float sm = e;
        #pragma unroll
        for (int off = 32; off; off >>= 1) sm += __shfl_xor(sm, off);
        if (lane < 49) S[row][lane] = e / sm;
    }
    __syncthreads();
    float* ob = O + (size_t)win * WIN * CC + head * HD;
    for (int idx = tid; idx < WIN * HD; idx += 256) {
        int i = idx >> 5, d = idx & 31;
        float acc = 0.f;
        #pragma unroll
        for (int j = 0; j < 49; j++) acc += S[i][j] * vs[j][d];
        ob[(size_t)i * CC + d] = acc;
    }
}

// ---------------- BN stats: column sums over token-major (NTOK, nch) ----------------
__global__ __launch_bounds__(256) void k_colstats(const float* __restrict__ Z,
                                                  float* __restrict__ sums, int nch) {
    int c = blockIdx.y * 256 + threadIdx.x;
    int t0 = blockIdx.x * 256;
    const float* zp = Z + (size_t)t0 * nch + c;
    float s = 0.f, sq = 0.f;
    for (int t = 0; t < 256; t++) {
        float v = zp[(size_t)t * nch];
        s += v; sq += v * v;
    }
    atomicAdd(&sums[c], s);
    atomicAdd(&sums[nch + c], sq);
}

__global__ void k_bnfin(const float* __restrict__ sums, const float* __restrict__ g,
                        const float* __restrict__ b, float* __restrict__ ss, int nch) {
    int c = blockIdx.x * 256 + threadIdx.x;
    if (c >= nch) return;
    float m = sums[c] * (1.0f / NTOK);
    float var = sums[nch + c] * (1.0f / NTOK) - m * m;
    float sc = rsqrtf(var + 1e-5f) * g[c];
    ss[c] = sc;
    ss[nch + c] = b[c] - m * sc;
}

// ---------------- elementwise gelu(bn(x)) in-place, float4 ----------------
__global__ __launch_bounds__(256) void k_act(float* __restrict__ Z,
                                             const float* __restrict__ ss,
                                             int nch, size_t total4) {
    size_t idx = (size_t)blockIdx.x * 256 + threadIdx.x;
    if (idx >= total4) return;
    float4 v = reinterpret_cast<float4*>(Z)[idx];
    int c0 = (int)((idx << 2) & (size_t)(nch - 1));
    v.x = gelu_f(v.x * ss[c0 + 0] + ss[nch + c0 + 0]);
    v.y = gelu_f(v.y * ss[c0 + 1] + ss[nch + c0 + 1]);
    v.z = gelu_f(v.z * ss[c0 + 2] + ss[nch + c0 + 2]);
    v.w = gelu_f(v.w * ss[c0 + 3] + ss[nch + c0 + 3]);
    reinterpret_cast<float4*>(Z)[idx] = v;
}

// ---------------- final elementwise: Z[i] = gelu(bn3(Z[i])) + XL[i], in-place ------
__global__ __launch_bounds__(256) void k_resfin(float* __restrict__ Z,
                                                const float* __restrict__ XL,
                                                const float* __restrict__ ss,
                                                size_t total4) {
    size_t idx = (size_t)blockIdx.x * 256 + threadIdx.x;
    if (idx >= total4) return;
    float4 v = reinterpret_cast<float4*>(Z)[idx];
    float4 xr = reinterpret_cast<const float4*>(XL)[idx];
    int c0 = (int)((idx << 2) & (size_t)(CC - 1));
    v.x = gelu_f(v.x * ss[c0 + 0] + ss[CC + c0 + 0]) + xr.x;
    v.y = gelu_f(v.y * ss[c0 + 1] + ss[CC + c0 + 1]) + xr.y;
    v.z = gelu_f(v.z * ss[c0 + 2] + ss[CC + c0 + 2]) + xr.z;
    v.w = gelu_f(v.w * ss[c0 + 3] + ss[CC + c0 + 3]) + xr.w;
    reinterpret_cast<float4*>(Z)[idx] = v;
}

// ---------------- depthwise 3x3 IN-PLACE over (H,W), token-major ----------------
// one block per (image, 32-channel chunk); 3-row rolling LDS buffer; rows done
// sequentially so the in-place write of row h never clobbers data still needed.
__global__ __launch_bounds__(256) void k_dwconv_ip(float* __restrict__ Z,
                                                   const float* __restrict__ wt,
                                                   const float* __restrict__ bias) {
    __shared__ float rb[3][56][32];
    const int b  = blockIdx.x >> 5;          // image
    const int c0 = (blockIdx.x & 31) * 32;   // channel chunk base
    const int tid = threadIdx.x;
    const int c = tid & 31, wg = tid >> 5;   // wg 0..7 -> w = wg*7 + i
    float* zb = Z + (size_t)b * HWW * HID + c0;
    float w9[9];
    #pragma unroll
    for (int k = 0; k < 9; k++) w9[k] = wt[(c0 + c) * 9 + k];
    const float bval = bias[c0 + c];

    // load rows 0 and 1
    for (int idx = tid; idx < 56 * 32; idx += 256) {
        int wcol = idx >> 5, ch = idx & 31;
        rb[0][wcol][ch] = zb[(size_t)(0 * 56 + wcol) * HID + ch];
        rb[1][wcol][ch] = zb[(size_t)(1 * 56 + wcol) * HID + ch];
    }
    __syncthreads();

    for (int h = 0; h < 56; ++h) {
        const int bm1 = (h + 2) % 3;   // holds row h-1 (slot reused for h+2)
        const int b0  = h % 3;         // row h
        const int bp1 = (h + 1) % 3;   // row h+1
        float outv[7];
        #pragma unroll
        for (int i = 0; i < 7; i++) {
            int w = wg * 7 + i;
            float acc = bval;
            #pragma unroll
            for (int kr = 0; kr < 3; kr++) {
                int hh = h + kr - 1;
                if (hh < 0 || hh >= 56) continue;
                const float (*row)[32] = (kr == 0) ? rb[bm1] : (kr == 1 ? rb[b0] : rb[bp1]);
                #pragma unroll
                for (int ks = 0; ks < 3; ks++) {
                    int ww = w + ks - 1;
                    if (ww < 0 || ww >= 56) continue;
                    acc += row[ww][c] * w9[kr * 3 + ks];
                }
            }
            outv[i] = acc;
        }
        #pragma unroll
        for (int i = 0; i < 7; i++)
            zb[(size_t)(h * 56 + wg * 7 + i) * HID + c] = outv[i];
        __syncthreads();                       // everyone done reading row h-1
        if (h + 2 < 56) {
            for (int idx = tid; idx < 56 * 32; idx += 256) {
                int wcol = idx >> 5, ch = idx & 31;
                rb[bm1][wcol][ch] = zb[(size_t)((h + 2) * 56 + wcol) * HID + ch];
            }
        }
        __syncthreads();
    }
}

// ---------------- fallback: zero output (diagnoses insufficient ws_size) ----------
__global__ __launch_bounds__(256) void k_zero(float* __restrict__ p, size_t n) {
    size_t i = (size_t)blockIdx.x * 256 + threadIdx.x;
    if (i < n) p[i] = 0.f;
}

// ---------------- host ----------------
// ws layout (floats):
//   XL   [12,845,056]                      residual stream (token-major)
//   BIGR [51,380,224]                      big region:
//        [0 .. 38,535,168)  = QKV  (phase A)   |  FFN hidden (phase B)
//        [38,535,168 .. end) = SCR posenc out (phase A) | FFN hidden tail (phase B)
//   SUMS [2*HID] SS1 [2*HID] SS2 [2*HID] SS3 [2*HID]
// total = 64,233,472 floats = 245.0 MiB.  d_out doubles as LN/attn/z3 scratch.
extern "C" void kernel_launch(void* const* d_in, const int* in_sizes, int n_in,
                              void* d_out, int out_size, void* d_ws, size_t ws_size,
                              hipStream_t stream) {
    const float* x      = (const float*)d_in[0];
    const float* ln1_w  = (const float*)d_in[1];
    const float* ln1_b  = (const float*)d_in[2];
    const float* pos_w1 = (const float*)d_in[3];
    const float* pos_w2 = (const float*)d_in[4];
    const float* qkv_w  = (const float*)d_in[5];
    const float* qkv_b  = (const float*)d_in[6];
    const float* rpb    = (const float*)d_in[7];
    const float* proj_w = (const float*)d_in[8];
    const float* proj_b = (const float*)d_in[9];
    const float* ln2_w  = (const float*)d_in[10];
    const float* ln2_b  = (const float*)d_in[11];
    const float* fc1_w  = (const float*)d_in[12];
    const float* fc1_b  = (const float*)d_in[13];
    const float* bn1_g  = (const float*)d_in[14];
    const float* bn1_b  = (const float*)d_in[15];
    const float* dw_w   = (const float*)d_in[16];
    const float* dw_b   = (const float*)d_in[17];
    const float* bn2_g  = (const float*)d_in[18];
    const float* bn2_b  = (const float*)d_in[19];
    const float* fc2_w  = (const float*)d_in[20];
    const float* fc2_b  = (const float*)d_in[21];
    const float* bn3_g  = (const float*)d_in[22];
    const float* bn3_b  = (const float*)d_in[23];
    float* OUT = (float*)d_out;

    const size_t SMALL = (size_t)NTOK * CC;   // 12,845,056 floats
    const size_t BIG   = (size_t)NTOK * HID;  // 51,380,224 floats
    const size_t QKVF  = (size_t)NTOK * C3;   // 38,535,168 floats
    const size_t NEED  = (SMALL + BIG + 8 * HID) * sizeof(float); // 256,966,656 B

    if (ws_size < NEED) {
        // clean diagnosable failure instead of an OOB crash
        k_zero<<<(unsigned)((SMALL + 255) / 256), 256, 0, stream>>>(OUT, SMALL);
        return;
    }

    float* ws = (float*)d_ws;
    float* XL   = ws;
    float* BIGR = XL + SMALL;
    float* SCR  = BIGR + QKVF;          // alias: tail of BIGR
    float* SUMS = BIGR + BIG;
    float* SS1  = SUMS + 2 * HID;
    float* SS2  = SS1 + 2 * HID;
    float* SS3  = SS2 + 2 * HID;

    dim3 tb(32, 8);
    dim3 tg(HWW / 32, CC / 32, BB);

    // XL = token-major(x)
    k_nchw_to_tok<<<tg, tb, 0, stream>>>(x, XL);
    // OUT = LN1(XL)   (d_out as scratch)
    k_ln<<<NTOK, 256, 0, stream>>>(XL, ln1_w, ln1_b, OUT);
    // SCR = windows + pos-enc  (tail of BIGR; head still unused)
    k_posenc<<<NWIN, 256, 0, stream>>>(OUT, pos_w1, pos_w2, SCR);
    // BIGR[0:QKVF) = qkv = SCR @ qkv_w^T + qkv_b    (M=50176, N=768, K=256)
    k_gemm_mfma<0><<<dim3(C3 / 128, NTOK / 128), 256, 0, stream>>>(SCR, qkv_w, qkv_b, BIGR, nullptr, C3, CC);
    // OUT = attention out per window token
    k_attn<<<NWIN * NHD, 256, 0, stream>>>(BIGR, rpb, OUT);
    // XL += unwindow(OUT @ proj_w^T + proj_b)
    k_gemm_mfma<1><<<dim3(CC / 128, NTOK / 128), 256, 0, stream>>>(OUT, proj_w, proj_b, nullptr, XL, CC, CC);
    // OUT = LN2(XL)
    k_ln<<<NTOK, 256, 0, stream>>>(XL, ln2_w, ln2_b, OUT);
    // BIGR = OUT @ fc1_w^T + fc1_b          (N=1024, K=256) — overwrites QKV+SCR
    k_gemm_mfma<0><<<dim3(HID / 128, NTOK / 128), 256, 0, stream>>>(OUT, fc1_w, fc1_b, BIGR, nullptr, HID, CC);
    // bn1 stats + gelu in-place
    hipMemsetAsync(SUMS, 0, 2 * HID * sizeof(float), stream);
    k_colstats<<<dim3(NTOK / 256, HID / 256), 256, 0, stream>>>(BIGR, SUMS, HID);
    k_bnfin<<<HID / 256, 256, 0, stream>>>(SUMS, bn1_g, bn1_b, SS1, HID);
    k_act<<<(unsigned)(BIG / 4 / 256), 256, 0, stream>>>(BIGR, SS1, HID, BIG / 4);
    // BIGR = dwconv(BIGR) + dw_b   (in-place)
    k_dwconv_ip<<<BB * 32, 256, 0, stream>>>(BIGR, dw_w, dw_b);
    // bn2 stats + gelu in-place
    hipMemsetAsync(SUMS, 0, 2 * HID * sizeof(float), stream);
    k_colstats<<<dim3(NTOK / 256, HID / 256), 256, 0, stream>>>(BIGR, SUMS, HID);
    k_bnfin<<<HID / 256, 256, 0, stream>>>(SUMS, bn2_g, bn2_b, SS2, HID);
    k_act<<<(unsigned)(BIG / 4 / 256), 256, 0, stream>>>(BIGR, SS2, HID, BIG / 4);
    // OUT = z3 = BIGR @ fc2_w^T + fc2_b     (N=256, K=1024)
    k_gemm_mfma<0><<<dim3(CC / 128, NTOK / 128), 256, 0, stream>>>(BIGR, fc2_w, fc2_b, OUT, nullptr, CC, HID);
    // bn3 stats on OUT
    hipMemsetAsync(SUMS, 0, 2 * CC * sizeof(float), stream);
    k_colstats<<<dim3(NTOK / 256, CC / 256), 256, 0, stream>>>(OUT, SUMS, CC);
    k_bnfin<<<1, 256, 0, stream>>>(SUMS, bn3_g, bn3_b, SS3, CC);
    // OUT = gelu(bn3(OUT)) + XL   (in-place elementwise)
    k_resfin<<<(unsigned)(SMALL / 4 / 256), 256, 0, stream>>>(OUT, XL, SS3, SMALL / 4);
    // XL = NCHW(OUT)  (XL dead now; transpose needs distinct src/dst)
    k_tok_to_nchw<<<tg, tb, 0, stream>>>(OUT, XL);
    // OUT = XL
    hipMemcpyAsync(OUT, XL, SMALL * sizeof(float), hipMemcpyDeviceToDevice, stream);
}

// Round 7
// 1270.141 us; speedup vs baseline: 1.2461x; 1.2461x over previous
//
#include <hip/hip_runtime.h>
#include <math.h>

#define BB 16
#define CC 256
#define HH 56
#define WW2 56
#define HWW 3136           // 56*56
#define NTOK 50176         // BB*HWW
#define NHD 8
#define HD 32
#define WSZ 7
#define WIN 49
#define NWIN 1024          // BB * 8 * 8
#define HID 1024
#define C3 768

typedef __attribute__((ext_vector_type(8))) short bf16x8;
typedef __attribute__((ext_vector_type(4))) float f32x4;
typedef unsigned short u16;

__device__ __forceinline__ float gelu_f(float x) {
    return 0.5f * x * (1.0f + erff(x * 0.70710678118654752f));
}
__device__ __forceinline__ float bf2f(u16 u) {
    return __uint_as_float(((unsigned)u) << 16);
}
__device__ __forceinline__ u16 f2bf(float f) {   // round-to-nearest-even
    unsigned u = __float_as_uint(f);
    u += 0x7FFFu + ((u >> 16) & 1u);
    return (u16)(u >> 16);
}

// ---------------- K1: NCHW -> token-major (b, p, c) ----------------
__global__ __launch_bounds__(256) void k_nchw_to_tok(const float* __restrict__ x,
                                                     float* __restrict__ xl) {
    __shared__ float tile[32][33];
    int b = blockIdx.z;
    int p0 = blockIdx.x * 32, c0 = blockIdx.y * 32;
    int tx = threadIdx.x, ty = threadIdx.y; // (32, 8)
    const float* xb = x + (size_t)b * CC * HWW;
    #pragma unroll
    for (int r = 0; r < 32; r += 8)
        tile[ty + r][tx] = xb[(size_t)(c0 + ty + r) * HWW + p0 + tx];
    __syncthreads();
    float* xlb = xl + (size_t)b * HWW * CC;
    #pragma unroll
    for (int r = 0; r < 32; r += 8)
        xlb[(size_t)(p0 + ty + r) * CC + c0 + tx] = tile[tx][ty + r];
}

// ---------------- K2: LayerNorm over C=256 per token ----------------
__global__ __launch_bounds__(256) void k_ln(const float* __restrict__ in,
                                            const float* __restrict__ w,
                                            const float* __restrict__ bia,
                                            float* __restrict__ out) {
    size_t t = blockIdx.x;
    int c = threadIdx.x;
    float v = in[t * CC + c];
    float s = v, sq = v * v;
    #pragma unroll
    for (int off = 32; off; off >>= 1) {
        s += __shfl_xor(s, off);
        sq += __shfl_xor(sq, off);
    }
    __shared__ float red[8];
    int wid = c >> 6, lane = c & 63;
    if (lane == 0) { red[wid] = s; red[4 + wid] = sq; }
    __syncthreads();
    s = red[0] + red[1] + red[2] + red[3];
    sq = red[4] + red[5] + red[6] + red[7];
    float m = s * (1.0f / CC);
    float var = sq * (1.0f / CC) - m * m;
    float rs = rsqrtf(var + 1e-6f);
    out[t * CC + c] = (v - m) * rs * w[c] + bia[c];
}

// ---------------- K3: window pos-enc (two depthwise 3x3 over 7x7 + gelu) ----------------
__global__ __launch_bounds__(256) void k_posenc(const float* __restrict__ xln,
                                                const float* __restrict__ w1,
                                                const float* __restrict__ w2,
                                                float* __restrict__ tout) {
    int win = blockIdx.x;
    int c = threadIdx.x;
    int b = win >> 6, wh = (win >> 3) & 7, ww = win & 7;
    const float* base = xln + ((size_t)b * HWW) * CC + c;
    float v[49];
    #pragma unroll
    for (int r = 0; r < 7; r++)
        #pragma unroll
        for (int s = 0; s < 7; s++)
            v[r * 7 + s] = base[(size_t)((wh * 7 + r) * WW2 + ww * 7 + s) * CC];
    float k1w[9], k2w[9];
    #pragma unroll
    for (int k = 0; k < 9; k++) { k1w[k] = w1[c * 9 + k]; k2w[k] = w2[c * 9 + k]; }
    float g[49];
    #pragma unroll
    for (int r = 0; r < 7; r++)
        #pragma unroll
        for (int s = 0; s < 7; s++) {
            float acc = 0.f;
            #pragma unroll
            for (int kr = 0; kr < 3; kr++)
                #pragma unroll
                for (int ks = 0; ks < 3; ks++) {
                    int rr = r + kr - 1, ss = s + ks - 1;
                    if (rr >= 0 && rr < 7 && ss >= 0 && ss < 7)
                        acc += v[rr * 7 + ss] * k1w[kr * 3 + ks];
                }
            g[r * 7 + s] = gelu_f(acc);
        }
    float* outp = tout + (size_t)win * WIN * CC + c;
    #pragma unroll
    for (int r = 0; r < 7; r++)
        #pragma unroll
        for (int s = 0; s < 7; s++) {
            float acc = 0.f;
            #pragma unroll
            for (int kr = 0; kr < 3; kr++)
                #pragma unroll
                for (int ks = 0; ks < 3; ks++) {
                    int rr = r + kr - 1, ss = s + ks - 1;
                    if (rr >= 0 && rr < 7 && ss >= 0 && ss < 7)
                        acc += g[rr * 7 + ss] * k2w[kr * 3 + ks];
                }
            outp[(size_t)(r * 7 + s) * CC] = v[r * 7 + s] + acc;
        }
}

// ---------------- split fp32 -> bf16 hi/lo (truncation; hi+lo exact to 2^-16 rel) ----
__device__ __forceinline__ void cvt_split4(float4 v, unsigned& h0, unsigned& h1,
                                           unsigned& l0, unsigned& l1) {
    unsigned ux = __float_as_uint(v.x), uy = __float_as_uint(v.y);
    unsigned uz = __float_as_uint(v.z), uw = __float_as_uint(v.w);
    unsigned hx = ux & 0xFFFF0000u, hy = uy & 0xFFFF0000u;
    unsigned hz = uz & 0xFFFF0000u, hw = uw & 0xFFFF0000u;
    float lx = v.x - __uint_as_float(hx);
    float ly = v.y - __uint_as_float(hy);
    float lz = v.z - __uint_as_float(hz);
    float lw = v.w - __uint_as_float(hw);
    h0 = (hx >> 16) | hy;
    h1 = (hz >> 16) | hw;
    l0 = (__float_as_uint(lx) >> 16) | (__float_as_uint(ly) & 0xFFFF0000u);
    l1 = (__float_as_uint(lz) >> 16) | (__float_as_uint(lw) & 0xFFFF0000u);
}

// ---------------- MFMA GEMM: Out[M,N] = A[M,K] @ Bw[N,K]^T + bias ----------------
// 128x128 tile, BK=32, 4 waves each 64x64, 16x16x32 bf16 MFMA, split 3-pass.
// EPI 0: fp32 store.  EPI 1: window-token remap + residual add (N==256).
// EPI 2: bf16 store (Out16).
#define LDK 40
template <int EPI>
__global__ __launch_bounds__(256) void k_gemm_mfma(const float* __restrict__ A,
                                                   const float* __restrict__ Bw,
                                                   const float* __restrict__ bias,
                                                   float* __restrict__ Out,
                                                   float* __restrict__ resid,
                                                   u16* __restrict__ Out16,
                                                   int N, int K) {
    __shared__ __align__(16) u16 Ah[128 * LDK];
    __shared__ __align__(16) u16 Al[128 * LDK];
    __shared__ __align__(16) u16 Bh[128 * LDK];
    __shared__ __align__(16) u16 Bl[128 * LDK];
    const int tid = threadIdx.x;
    const int bm = blockIdx.y * 128;
    const int bn = blockIdx.x * 128;
    const int srow = tid >> 3;
    const int skf = (tid & 7) * 4;
    const int lane = tid & 63;
    const int wave = tid >> 6;
    const int wm = (wave & 1) * 64;
    const int wn = (wave >> 1) * 64;
    const int frow = lane & 15;
    const int fk = (lane >> 4) * 8;

    f32x4 acc[4][4] = {};

    for (int k0 = 0; k0 < K; k0 += 32) {
        if (k0) __syncthreads();
        #pragma unroll
        for (int h = 0; h < 4; ++h) {
            int row = srow + h * 32;
            float4 av = *reinterpret_cast<const float4*>(&A[(size_t)(bm + row) * K + k0 + skf]);
            float4 bv = *reinterpret_cast<const float4*>(&Bw[(size_t)(bn + row) * K + k0 + skf]);
            unsigned h0, h1, l0, l1;
            cvt_split4(av, h0, h1, l0, l1);
            *reinterpret_cast<uint2*>(&Ah[row * LDK + skf]) = make_uint2(h0, h1);
            *reinterpret_cast<uint2*>(&Al[row * LDK + skf]) = make_uint2(l0, l1);
            cvt_split4(bv, h0, h1, l0, l1);
            *reinterpret_cast<uint2*>(&Bh[row * LDK + skf]) = make_uint2(h0, h1);
            *reinterpret_cast<uint2*>(&Bl[row * LDK + skf]) = make_uint2(l0, l1);
        }
        __syncthreads();
        bf16x8 a_h[4], a_l[4], b_h[4], b_l[4];
        #pragma unroll
        for (int mi = 0; mi < 4; mi++) {
            int idx = (wm + mi * 16 + frow) * LDK + fk;
            a_h[mi] = *reinterpret_cast<const bf16x8*>(&Ah[idx]);
            a_l[mi] = *reinterpret_cast<const bf16x8*>(&Al[idx]);
        }
        #pragma unroll
        for (int nj = 0; nj < 4; nj++) {
            int idx = (wn + nj * 16 + frow) * LDK + fk;
            b_h[nj] = *reinterpret_cast<const bf16x8*>(&Bh[idx]);
            b_l[nj] = *reinterpret_cast<const bf16x8*>(&Bl[idx]);
        }
        #pragma unroll
        for (int mi = 0; mi < 4; mi++)
            #pragma unroll
            for (int nj = 0; nj < 4; nj++) {
                acc[mi][nj] = __builtin_amdgcn_mfma_f32_16x16x32_bf16(a_h[mi], b_h[nj], acc[mi][nj], 0, 0, 0);
                acc[mi][nj] = __builtin_amdgcn_mfma_f32_16x16x32_bf16(a_l[mi], b_h[nj], acc[mi][nj], 0, 0, 0);
                acc[mi][nj] = __builtin_amdgcn_mfma_f32_16x16x32_bf16(a_h[mi], b_l[nj], acc[mi][nj], 0, 0, 0);
            }
    }

    const int rbase = (lane >> 4) * 4;
    #pragma unroll
    for (int mi = 0; mi < 4; mi++) {
        #pragma unroll
        for (int nj = 0; nj < 4; nj++) {
            int gcol = bn + wn + nj * 16 + frow;
            float bval = bias[gcol];
            #pragma unroll
            for (int r = 0; r < 4; r++) {
                int grow = bm + wm + mi * 16 + rbase + r;
                float val = acc[mi][nj][r] + bval;
                if (EPI == 0) {
                    Out[(size_t)grow * N + gcol] = val;
                } else if (EPI == 1) {
                    int win = grow / 49, ii = grow - win * 49;
                    int b = win >> 6, wh = (win >> 3) & 7, ww = win & 7;
                    int rr = ii / 7, ss = ii - rr * 7;
                    size_t tok = (size_t)b * HWW + (size_t)((wh * 7 + rr) * WW2 + ww * 7 + ss);
                    resid[tok * CC + gcol] += val;
                } else {
                    Out16[(size_t)grow * N + gcol] = f2bf(val);
                }
            }
        }
    }
}

// ---------------- fc2 GEMM: A = bf16 hidden (act2 fused on load), 2-pass ----------
// Out[M=token][N=256] fp32 = gelu(bn2(A16)) @ Bw[N][K]^T + bias
__global__ __launch_bounds__(256) void k_gemm_a16(const u16* __restrict__ A16,
                                                  const float* __restrict__ ss2,
                                                  const float* __restrict__ Bw,
                                                  const float* __restrict__ bias,
                                                  float* __restrict__ Out,
                                                  int N, int K) {
    __shared__ __align__(16) u16 Ah[128 * LDK];
    __shared__ __align__(16) u16 Bh[128 * LDK];
    __shared__ __align__(16) u16 Bl[128 * LDK];
    const int tid = threadIdx.x;
    const int bm = blockIdx.y * 128;
    const int bn = blockIdx.x * 128;
    const int r2 = tid >> 2;          // 0..63
    const int kh = (tid & 3) * 8;     // bf16 k-offset 0,8,16,24
    const int srow = tid >> 3;
    const int skf = (tid & 7) * 4;
    const int lane = tid & 63;
    const int wave = tid >> 6;
    const int wm = (wave & 1) * 64;
    const int wn = (wave >> 1) * 64;
    const int frow = lane & 15;
    const int fk = (lane >> 4) * 8;

    f32x4 acc[4][4] = {};

    for (int k0 = 0; k0 < K; k0 += 32) {
        if (k0) __syncthreads();
        // stage A (bf16 + fused gelu(bn2))
        #pragma unroll
        for (int h = 0; h < 2; ++h) {
            int row = r2 + h * 64;
            uint4 av = *reinterpret_cast<const uint4*>(&A16[(size_t)(bm + row) * K + k0 + kh]);
            const u16* ap = reinterpret_cast<const u16*>(&av);
            float4 s0 = *reinterpret_cast<const float4*>(&ss2[k0 + kh]);
            float4 s1 = *reinterpret_cast<const float4*>(&ss2[k0 + kh + 4]);
            float4 t0 = *reinterpret_cast<const float4*>(&ss2[HID + k0 + kh]);
            float4 t1 = *reinterpret_cast<const float4*>(&ss2[HID + k0 + kh + 4]);
            u16 o8[8];
            o8[0] = f2bf(gelu_f(bf2f(ap[0]) * s0.x + t0.x));
            o8[1] = f2bf(gelu_f(bf2f(ap[1]) * s0.y + t0.y));
            o8[2] = f2bf(gelu_f(bf2f(ap[2]) * s0.z + t0.z));
            o8[3] = f2bf(gelu_f(bf2f(ap[3]) * s0.w + t0.w));
            o8[4] = f2bf(gelu_f(bf2f(ap[4]) * s1.x + t1.x));
            o8[5] = f2bf(gelu_f(bf2f(ap[5]) * s1.y + t1.y));
            o8[6] = f2bf(gelu_f(bf2f(ap[6]) * s1.z + t1.z));
            o8[7] = f2bf(gelu_f(bf2f(ap[7]) * s1.w + t1.w));
            *reinterpret_cast<uint4*>(&Ah[row * LDK + kh]) = *reinterpret_cast<uint4*>(o8);
        }
        // stage B (fp32 split)
        #pragma unroll
        for (int h = 0; h < 4; ++h) {
            int row = srow + h * 32;
            float4 bv = *reinterpret_cast<const float4*>(&Bw[(size_t)(bn + row) * K + k0 + skf]);
            unsigned h0, h1, l0, l1;
            cvt_split4(bv, h0, h1, l0, l1);
            *reinterpret_cast<uint2*>(&Bh[row * LDK + skf]) = make_uint2(h0, h1);
            *reinterpret_cast<uint2*>(&Bl[row * LDK + skf]) = make_uint2(l0, l1);
        }
        __syncthreads();
        bf16x8 a_h[4], b_h[4], b_l[4];
        #pragma unroll
        for (int mi = 0; mi < 4; mi++)
            a_h[mi] = *reinterpret_cast<const bf16x8*>(&Ah[(wm + mi * 16 + frow) * LDK + fk]);
        #pragma unroll
        for (int nj = 0; nj < 4; nj++) {
            int idx = (wn + nj * 16 + frow) * LDK + fk;
            b_h[nj] = *reinterpret_cast<const bf16x8*>(&Bh[idx]);
            b_l[nj] = *reinterpret_cast<const bf16x8*>(&Bl[idx]);
        }
        #pragma unroll
        for (int mi = 0; mi < 4; mi++)
            #pragma unroll
            for (int nj = 0; nj < 4; nj++) {
                acc[mi][nj] = __builtin_amdgcn_mfma_f32_16x16x32_bf16(a_h[mi], b_h[nj], acc[mi][nj], 0, 0, 0);
                acc[mi][nj] = __builtin_amdgcn_mfma_f32_16x16x32_bf16(a_h[mi], b_l[nj], acc[mi][nj], 0, 0, 0);
            }
    }

    const int rbase = (lane >> 4) * 4;
    #pragma unroll
    for (int mi = 0; mi < 4; mi++)
        #pragma unroll
        for (int nj = 0; nj < 4; nj++) {
            int gcol = bn + wn + nj * 16 + frow;
            float bval = bias[gcol];
            #pragma unroll
            for (int r = 0; r < 4; r++) {
                int grow = bm + wm + mi * 16 + rbase + r;
                Out[(size_t)grow * N + gcol] = acc[mi][nj][r] + bval;
            }
        }
}

// ---------------- K5: windowed attention, one (win, head) per block ----------------
__global__ __launch_bounds__(256) void k_attn(const float* __restrict__ qkv,
                                              const float* __restrict__ rpb,
                                              float* __restrict__ O) {
    __shared__ float qs[49][32], ks[49][32], vs[49][32];
    __shared__ float S[49][52];
    const int tid = threadIdx.x;
    const int win = blockIdx.x >> 3;
    const int head = blockIdx.x & 7;
    const float* base = qkv + (size_t)win * WIN * C3 + head * HD;
    for (int idx = tid; idx < WIN * HD; idx += 256) {
        int i = idx >> 5, d = idx & 31;
        const float* bp = base + (size_t)i * C3 + d;
        qs[i][d] = bp[0] * 0.17677669529663687f;
        ks[i][d] = bp[CC];
        vs[i][d] = bp[2 * CC];
    }
    __syncthreads();
    for (int idx = tid; idx < WIN * WIN; idx += 256) {
        int i = idx / 49, j = idx - i * 49;
        const float4* qp = reinterpret_cast<const float4*>(qs[i]);
        const float4* kp = reinterpret_cast<const float4*>(ks[j]);
        float acc = 0.f;
        #pragma unroll
        for (int d = 0; d < 8; d++) {
            float4 a = qp[d], b2 = kp[d];
            acc += a.x * b2.x + a.y * b2.y + a.z * b2.z + a.w * b2.w;
        }
        int ci = (i / 7) * 13 + (i % 7);
        int jr = 48 - j;
        int cj = (jr / 7) * 13 + (jr % 7);
        S[i][j] = acc + rpb[(ci + cj) * NHD + head];
    }
    __syncthreads();
    int wid = tid >> 6, lane = tid & 63;
    for (int row = wid; row < 49; row += 4) {
        float v = (lane < 49) ? S[row][lane] : -1e30f;
        float mx = v;
        #pragma unroll
        for (int off = 32; off; off >>= 1) mx = fmaxf(mx, __shfl_xor(mx, off));
        float e = (lane < 49) ? __expf(v - mx) : 0.f;
        float sm = e;
        #pragma unroll
        for (int off = 32; off; off >>= 1) sm += __shfl_xor(sm, off);
        if (lane < 49) S[row][lane] = e / sm;
    }
    __syncthreads();
    float* ob = O + (size_t)win * WIN * CC + head * HD;
    for (int idx = tid; idx < WIN * HD; idx += 256) {
        int i = idx >> 5, d = idx & 31;
        float acc = 0.f;
        #pragma unroll
        for (int j = 0; j < 49; j++) acc += S[i][j] * vs[j][d];
        ob[(size_t)i * CC + d] = acc;
    }
}

// ---------------- BN stats fp32 (token-major) ----------------
__global__ __launch_bounds__(256) void k_colstats(const float* __restrict__ Z,
                                                  float* __restrict__ sums, int nch) {
    int c = blockIdx.y * 256 + threadIdx.x;
    int t0 = blockIdx.x * 256;
    const float* zp = Z + (size_t)t0 * nch + c;
    float s = 0.f, sq = 0.f;
    for (int t = 0; t < 256; t++) {
        float v = zp[(size_t)t * nch];
        s += v; sq += v * v;
    }
    atomicAdd(&sums[c], s);
    atomicAdd(&sums[nch + c], sq);
}

// ---------------- BN stats bf16 (token-major) ----------------
__global__ __launch_bounds__(256) void k_colstats16(const u16* __restrict__ Z,
                                                    float* __restrict__ sums, int nch) {
    int c = blockIdx.y * 256 + threadIdx.x;
    int t0 = blockIdx.x * 256;
    const u16* zp = Z + (size_t)t0 * nch + c;
    float s = 0.f, sq = 0.f;
    for (int t = 0; t < 256; t++) {
        float v = bf2f(zp[(size_t)t * nch]);
        s += v; sq += v * v;
    }
    atomicAdd(&sums[c], s);
    atomicAdd(&sums[nch + c], sq);
}

__global__ void k_bnfin(const float* __restrict__ sums, const float* __restrict__ g,
                        const float* __restrict__ b, float* __restrict__ ss, int nch) {
    int c = blockIdx.x * 256 + threadIdx.x;
    if (c >= nch) return;
    float m = sums[c] * (1.0f / NTOK);
    float var = sums[nch + c] * (1.0f / NTOK) - m * m;
    float sc = rsqrtf(var + 1e-5f) * g[c];
    ss[c] = sc;
    ss[nch + c] = b[c] - m * sc;
}

// ---------------- depthwise 3x3, token-major bf16, out-of-place -----------------
// fused: input act = gelu(bn1(x)); output: bf16 store + bn2 partial stats.
// block = (image, 8-row band, 32-channel chunk): 16*7*32 = 3584 blocks.
__global__ __launch_bounds__(256) void k_dwconv_tok(const u16* __restrict__ Zin,
                                                    const float* __restrict__ ss1,
                                                    const float* __restrict__ wt,
                                                    const float* __restrict__ bias,
                                                    u16* __restrict__ Zout,
                                                    float* __restrict__ sums2) {
    __shared__ u16 sm[10][56][32];
    __shared__ float rs[256], rq[256];
    const int bx = blockIdx.x;
    const int b = bx / 224;
    const int rem = bx - b * 224;
    const int band = rem >> 5;           // 0..6
    const int chk = rem & 31;            // 0..31
    const int c0 = chk * 32;
    const int h0 = band * 8;
    const int tid = threadIdx.x;

    // load 10 rows (h0-1 .. h0+8), activated, into LDS
    for (int idx = tid; idx < 10 * 56 * 4; idx += 256) {
        int chunk = idx & 3;
        int q = idx >> 2;
        int row = q / 56;
        int pix = q - row * 56;
        int h = h0 - 1 + row;
        u16 o8[8];
        if (h < 0 || h >= HH) {
            #pragma unroll
            for (int j = 0; j < 8; j++) o8[j] = 0;
        } else {
            size_t off = ((size_t)(b * HWW + h * WW2 + pix)) * HID + c0 + chunk * 8;
            uint4 av = *reinterpret_cast<const uint4*>(&Zin[off]);
            const u16* ap = reinterpret_cast<const u16*>(&av);
            #pragma unroll
            for (int j = 0; j < 8; j++) {
                int cc = c0 + chunk * 8 + j;
                float v = bf2f(ap[j]);
                o8[j] = f2bf(gelu_f(v * ss1[cc] + ss1[HID + cc]));
            }
        }
        *reinterpret_cast<uint4*>(&sm[row][pix][chunk * 8]) = *reinterpret_cast<uint4*>(o8);
    }
    __syncthreads();

    const int c = tid & 31;
    const int wg = tid >> 5;             // 0..7 -> w = wg*7 + i
    const int wbase = wg * 7;
    float w9[9];
    #pragma unroll
    for (int k = 0; k < 9; k++) w9[k] = wt[(c0 + c) * 9 + k];
    const float bval = bias[c0 + c];
    const bool lok = (wbase > 0);
    const bool rok = (wbase + 7 < WW2);

    float win[3][9];
    // preload sm rows 0,1 into win[0], win[1]
    #pragma unroll
    for (int r = 0; r < 2; r++) {
        win[r][0] = lok ? bf2f(sm[r][wbase - 1][c]) : 0.f;
        #pragma unroll
        for (int j = 0; j < 7; j++) win[r][1 + j] = bf2f(sm[r][wbase + j][c]);
        win[r][8] = rok ? bf2f(sm[r][wbase + 7][c]) : 0.f;
    }

    float s = 0.f, sq = 0.f;
    u16* zb = Zout + ((size_t)(b * HWW + h0 * WW2)) * HID + c0 + c;
    #pragma unroll
    for (int hh = 0; hh < 8; ++hh) {
        const int rn = (hh + 2) % 3;
        // load sm row hh+2
        win[rn][0] = lok ? bf2f(sm[hh + 2][wbase - 1][c]) : 0.f;
        #pragma unroll
        for (int j = 0; j < 7; j++) win[rn][1 + j] = bf2f(sm[hh + 2][wbase + j][c]);
        win[rn][8] = rok ? bf2f(sm[hh + 2][wbase + 7][c]) : 0.f;
        const int r0 = hh % 3, r1 = (hh + 1) % 3, r2 = (hh + 2) % 3;
        #pragma unroll
        for (int i = 0; i < 7; i++) {
            float acc = bval;
            acc += win[r0][i] * w9[0] + win[r0][i + 1] * w9[1] + win[r0][i + 2] * w9[2];
            acc += win[r1][i] * w9[3] + win[r1][i + 1] * w9[4] + win[r1][i + 2] * w9[5];
            acc += win[r2][i] * w9[6] + win[r2][i + 1] * w9[7] + win[r2][i + 2] * w9[8];
            zb[(size_t)(hh * WW2 + wbase + i) * HID] = f2bf(acc);
            s += acc; sq += acc * acc;
        }
    }
    // bn2 partial stats: reduce 8 wg's per channel, then atomics
    rs[tid] = s; rq[tid] = sq;
    __syncthreads();
    if (tid < 32) {
        float st = 0.f, qt = 0.f;
        #pragma unroll
        for (int g = 0; g < 8; g++) { st += rs[g * 32 + tid]; qt += rq[g * 32 + tid]; }
        atomicAdd(&sums2[c0 + tid], st);
        atomicAdd(&sums2[HID + c0 + tid], qt);
    }
}

// ---------------- final: out[b,c,p] = gelu(bn3(z3)) + xl, token-major -> NCHW -----
__global__ __launch_bounds__(256) void k_final(const float* __restrict__ Z3,
                                               const float* __restrict__ XL,
                                               const float* __restrict__ ss,
                                               float* __restrict__ out) {
    __shared__ float tile[32][33];
    int b = blockIdx.z, p0 = blockIdx.x * 32, c0 = blockIdx.y * 32;
    int tx = threadIdx.x, ty = threadIdx.y;
    const float* zb = Z3 + (size_t)b * HWW * CC;
    const float* xb = XL + (size_t)b * HWW * CC;
    #pragma unroll
    for (int r = 0; r < 32; r += 8) {
        int p = p0 + ty + r, c = c0 + tx;
        float v = zb[(size_t)p * CC + c];
        tile[ty + r][tx] = gelu_f(v * ss[c] + ss[CC + c]) + xb[(size_t)p * CC + c];
    }
    __syncthreads();
    float* ob = out + (size_t)b * CC * HWW;
    #pragma unroll
    for (int r = 0; r < 32; r += 8) {
        int c = c0 + ty + r, p = p0 + tx;
        ob[(size_t)c * HWW + p] = tile[tx][ty + r];
    }
}

// ---------------- fallback: zero output (diagnoses insufficient ws_size) ----------
__global__ __launch_bounds__(256) void k_zero(float* __restrict__ p, size_t n) {
    size_t i = (size_t)blockIdx.x * 256 + threadIdx.x;
    if (i < n) p[i] = 0.f;
}

// ---------------- host ----------------
// ws (floats): XL[12.8M] | R[51.4M]  | SUMS/SS[8K]        total 245.0 MiB
//   R phase A: SCR fp32 [SMALL] + QKV fp32 [NTOK*768]   (= exactly R)
//   R phase B: H16A bf16 [NTOK*1024] + H16B bf16 [NTOK*1024]  (= exactly R)
//   R phase C: FR fp32 [SMALL] (final NCHW staging)
extern "C" void kernel_launch(void* const* d_in, const int* in_sizes, int n_in,
                              void* d_out, int out_size, void* d_ws, size_t ws_size,
                              hipStream_t stream) {
    const float* x      = (const float*)d_in[0];
    const float* ln1_w  = (const float*)d_in[1];
    const float* ln1_b  = (const float*)d_in[2];
    const float* pos_w1 = (const float*)d_in[3];
    const float* pos_w2 = (const float*)d_in[4];
    const float* qkv_w  = (const float*)d_in[5];
    const float* qkv_b  = (const float*)d_in[6];
    const float* rpb    = (const float*)d_in[7];
    const float* proj_w = (const float*)d_in[8];
    const float* proj_b = (const float*)d_in[9];
    const float* ln2_w  = (const float*)d_in[10];
    const float* ln2_b  = (const float*)d_in[11];
    const float* fc1_w  = (const float*)d_in[12];
    const float* fc1_b  = (const float*)d_in[13];
    const float* bn1_g  = (const float*)d_in[14];
    const float* bn1_b  = (const float*)d_in[15];
    const float* dw_w   = (const float*)d_in[16];
    const float* dw_b   = (const float*)d_in[17];
    const float* bn2_g  = (const float*)d_in[18];
    const float* bn2_b  = (const float*)d_in[19];
    const float* fc2_w  = (const float*)d_in[20];
    const float* fc2_b  = (const float*)d_in[21];
    const float* bn3_g  = (const float*)d_in[22];
    const float* bn3_b  = (const float*)d_in[23];
    float* OUT = (float*)d_out;

    const size_t SMALL = (size_t)NTOK * CC;   // 12,845,056 floats
    const size_t BIG   = (size_t)NTOK * HID;  // 51,380,224 floats
    const size_t NEED  = (SMALL + BIG + 8 * HID) * sizeof(float);

    if (ws_size < NEED) {
        k_zero<<<(unsigned)((SMALL + 255) / 256), 256, 0, stream>>>(OUT, SMALL);
        return;
    }

    float* ws = (float*)d_ws;
    float* XL   = ws;
    float* R    = XL + SMALL;
    float* SCR  = R;                          // phase A
    float* QKV  = R + SMALL;                  // phase A
    u16*   H16A = (u16*)R;                    // phase B (BIG bf16)
    u16*   H16B = H16A + BIG;                 // phase B (BIG bf16)
    float* FR   = R;                          // phase C
    float* SUMS = R + BIG;
    float* SS1  = SUMS + 2 * HID;
    float* SS2  = SS1 + 2 * HID;
    float* SS3  = SS2 + 2 * HID;

    dim3 tb(32, 8);
    dim3 tg(HWW / 32, CC / 32, BB);

    // ---- attention phase ----
    k_nchw_to_tok<<<tg, tb, 0, stream>>>(x, XL);
    k_ln<<<NTOK, 256, 0, stream>>>(XL, ln1_w, ln1_b, OUT);
    k_posenc<<<NWIN, 256, 0, stream>>>(OUT, pos_w1, pos_w2, SCR);
    k_gemm_mfma<0><<<dim3(C3 / 128, NTOK / 128), 256, 0, stream>>>(SCR, qkv_w, qkv_b, QKV, nullptr, nullptr, C3, CC);
    k_attn<<<NWIN * NHD, 256, 0, stream>>>(QKV, rpb, OUT);
    k_gemm_mfma<1><<<dim3(CC / 128, NTOK / 128), 256, 0, stream>>>(OUT, proj_w, proj_b, nullptr, XL, nullptr, CC, CC);
    // ---- FFN phase ----
    k_ln<<<NTOK, 256, 0, stream>>>(XL, ln2_w, ln2_b, OUT);
    k_gemm_mfma<2><<<dim3(HID / 128, NTOK / 128), 256, 0, stream>>>(OUT, fc1_w, fc1_b, nullptr, nullptr, H16A, HID, CC);
    hipMemsetAsync(SUMS, 0, 2 * HID * sizeof(float), stream);
    k_colstats16<<<dim3(NTOK / 256, HID / 256), 256, 0, stream>>>(H16A, SUMS, HID);
    k_bnfin<<<HID / 256, 256, 0, stream>>>(SUMS, bn1_g, bn1_b, SS1, HID);
    hipMemsetAsync(SUMS, 0, 2 * HID * sizeof(float), stream);
    k_dwconv_tok<<<BB * 7 * 32, 256, 0, stream>>>(H16A, SS1, dw_w, dw_b, H16B, SUMS);
    k_bnfin<<<HID / 256, 256, 0, stream>>>(SUMS, bn2_g, bn2_b, SS2, HID);
    k_gemm_a16<<<dim3(CC / 128, NTOK / 128), 256, 0, stream>>>(H16B, SS2, fc2_w, fc2_b, OUT, CC, HID);
    hipMemsetAsync(SUMS, 0, 2 * CC * sizeof(float), stream);
    k_colstats<<<dim3(NTOK / 256, CC / 256), 256, 0, stream>>>(OUT, SUMS, CC);
    k_bnfin<<<1, 256, 0, stream>>>(SUMS, bn3_g, bn3_b, SS3, CC);
    // ---- epilogue: fused bn3+gelu+residual+transpose into FR, then copy out ----
    k_final<<<tg, tb, 0, stream>>>(OUT, XL, SS3, FR);
    hipMemcpyAsync(OUT, FR, SMALL * sizeof(float), hipMemcpyDeviceToDevice, stream);
}